// Round 5
// baseline (61729.865 us; speedup 1.0000x reference)
//
#include <hip/hip_runtime.h>

// ---------------------------------------------------------------------------
// GRUNet: one flattened 8192-step 2-layer GRU scan (phase 1), a 256-step
// 2-layer GRU scan over sampled states (phase 2), then 2 tiny FCs -> 2 floats.
// 256 WGs (one per CU), each WG owns 4 h-elems; per-step cross-WG broadcast.
// Round 5: hierarchical XCD-aware broadcast. Rounds 1-4 proved the critical
// path is sync latency (compute changes didn't move 26-28ms): 131K threads
// polling the MALL with sc1 loads every round. Now only 8 relay WGs (one per
// XCD, self-elected via HW_REG_XCC_ID + atomicCAS) poll the MALL; they
// republish into per-XCD mirrors (sc0 -> own L2); consumers poll their own
// XCD's mirror with sc0 loads (local L2 RTT ~0.2us vs MALL ~1us), with a
// 1-in-64 sc1 global fallback so no hang is possible regardless of cache
// semantics.
// ---------------------------------------------------------------------------

typedef unsigned u32x4 __attribute__((ext_vector_type(4)));
typedef unsigned u32x2 __attribute__((ext_vector_type(2)));
typedef _Float16 h2_t  __attribute__((ext_vector_type(2)));

#define NWG 256

__device__ u32x4    g_recL0[2][NWG];     // layer-0 h records: {pair0,pair1,tag,0}
__device__ u32x4    g_recL1[2][NWG];     // layer-1 h records
__device__ u32x4    g_mirror[8][2][512]; // per-XCD mirror of the 512 records
__device__ int      g_relay[8];          // relay blockIdx per XCD (-1 = none)
__device__ unsigned g_seq2[256][512];    // sampled states (f16 pairs) for gru2

// ---- f16 pack/unpack (RNE) ----
__device__ __forceinline__ unsigned pk(float a, float b) {
  unsigned short ua = __builtin_bit_cast(unsigned short, (_Float16)a);
  unsigned short ub = __builtin_bit_cast(unsigned short, (_Float16)b);
  return (unsigned)ua | ((unsigned)ub << 16);
}
__device__ __forceinline__ float unpk(unsigned u, int hi) {
  unsigned short us = (unsigned short)(hi ? (u >> 16) : (u & 0xffffu));
  return (float)__builtin_bit_cast(_Float16, us);
}

// ---- dot2: f16x2 * f16x2 + f32 ----
#if __has_builtin(__builtin_amdgcn_fdot2)
__device__ __forceinline__ float fdot2(unsigned a, unsigned b, float c) {
  return __builtin_amdgcn_fdot2(__builtin_bit_cast(h2_t, a),
                                __builtin_bit_cast(h2_t, b), c, false);
}
#else
__device__ __forceinline__ float fdot2(unsigned a, unsigned b, float c) {
  h2_t ha = __builtin_bit_cast(h2_t, a), hb = __builtin_bit_cast(h2_t, b);
  return c + (float)ha[0] * (float)hb[0] + (float)ha[1] * (float)hb[1];
}
#endif

// ---- scoped vector load/store ----
// sc1: coherent at MALL/L3 (cross-XCD).  sc0: coherent at own-XCD L2.
__device__ __forceinline__ u32x4 ld_sc_v4(const u32x4* p) {
  u32x4 v;
  asm volatile("global_load_dwordx4 %0, %1, off sc1\n\t"
               "s_waitcnt vmcnt(0)"
               : "=&v"(v) : "v"(p) : "memory");
  return v;
}
__device__ __forceinline__ u32x4 ld_l2_v4(const u32x4* p) {
  u32x4 v;
  asm volatile("global_load_dwordx4 %0, %1, off sc0\n\t"
               "s_waitcnt vmcnt(0)"
               : "=&v"(v) : "v"(p) : "memory");
  return v;
}
__device__ __forceinline__ void st_sc_v4(u32x4* p, u32x4 v) {
  asm volatile("global_store_dwordx4 %0, %1, off sc1"
               :: "v"(p), "v"(v) : "memory");
}
__device__ __forceinline__ void st_l2_v4(u32x4* p, u32x4 v) {
  asm volatile("global_store_dwordx4 %0, %1, off sc0"
               :: "v"(p), "v"(v) : "memory");
}
__device__ __forceinline__ void st_sc_v2(void* p, u32x2 v) {
  asm volatile("global_store_dwordx2 %0, %1, off sc1"
               :: "v"(p), "v"(v) : "memory");
}

// ---- fast activations (clamped; f16-noise-dominated error budget) ----
__device__ __forceinline__ float rcpf(float x) {
#if __has_builtin(__builtin_amdgcn_rcpf)
  return __builtin_amdgcn_rcpf(x);
#else
  return 1.f / x;
#endif
}
__device__ __forceinline__ float sigf(float x) {
  return rcpf(1.f + __expf(-x));
}
__device__ __forceinline__ float tanh_f(float x) {
  x = fminf(fmaxf(x, -15.f), 15.f);
  const float e = __expf(2.f * x);
  return (e - 1.f) * rcpf(e + 1.f);
}

// ---- LDS swizzles (16B-chunk XOR) ----
__device__ __forceinline__ int swzHc(int ch) { return ch ^ ((ch >> 3) & 7); } // 128-chunk bufs
__device__ __forceinline__ int swzXc(int ch) { return ch ^ ((ch >> 2) & 7); } // 64-chunk buf
__device__ __forceinline__ int swzH_pos(int idx) { return (swzHc(idx >> 2) << 2) | (idx & 3); }
__device__ __forceinline__ int swzX_pos(int idx) { return (swzXc(idx >> 2) << 2) | (idx & 3); }

__global__ void init_recs() {
  int t = blockIdx.x * blockDim.x + threadIdx.x;  // <<<40,256>>> = 10240
  u32x4 ff = {0u, 0u, 0xFFFFFFFFu, 0u};           // tag never matches a step
  if (t < 512)              g_recL0[t >> 8][t & 255] = ff;
  else if (t < 1024)        g_recL1[(t - 512) >> 8][t & 255] = ff;
  else if (t < 1024 + 8192) ((u32x4*)g_mirror)[t - 1024] = ff;
  if (t < 8) g_relay[t] = -1;
}

// Fill 4 vectors (16 u32 = 32 cols) of one weight row from float4 loads.
#define LDROW16(T, A, B, C, D)                                                 \
  {                                                                            \
    const int rr = g4 * 3 + (T);                                               \
    const float4* r4 = (const float4*)(Wm + (size_t)((rr >> 2) * 1024 + j0 +   \
                       (rr & 3)) * cols + kh * (cols >> 1) + q * (cols >> 5)); \
    float4 v;                                                                  \
    v = r4[0]; A[0] = pk(v.x, v.y); A[1] = pk(v.z, v.w);                       \
    v = r4[1]; A[2] = pk(v.x, v.y); A[3] = pk(v.z, v.w);                       \
    v = r4[2]; B[0] = pk(v.x, v.y); B[1] = pk(v.z, v.w);                       \
    v = r4[3]; B[2] = pk(v.x, v.y); B[3] = pk(v.z, v.w);                       \
    v = r4[4]; C[0] = pk(v.x, v.y); C[1] = pk(v.z, v.w);                       \
    v = r4[5]; C[2] = pk(v.x, v.y); C[3] = pk(v.z, v.w);                       \
    v = r4[6]; D[0] = pk(v.x, v.y); D[1] = pk(v.z, v.w);                       \
    v = r4[7]; D[2] = pk(v.x, v.y); D[3] = pk(v.z, v.w);                       \
  }

// Fill 2 vectors (8 u32 = 16 cols) of one weight row (512-col matrix).
#define LDROW8(T, A, B)                                                        \
  {                                                                            \
    const int rr = g4 * 3 + (T);                                               \
    const float4* r4 = (const float4*)(Wm + (size_t)((rr >> 2) * 1024 + j0 +   \
                       (rr & 3)) * cols + kh * (cols >> 1) + q * (cols >> 5)); \
    float4 v;                                                                  \
    v = r4[0]; A[0] = pk(v.x, v.y); A[1] = pk(v.z, v.w);                       \
    v = r4[1]; A[2] = pk(v.x, v.y); A[3] = pk(v.z, v.w);                       \
    v = r4[2]; B[0] = pk(v.x, v.y); B[1] = pk(v.z, v.w);                       \
    v = r4[3]; B[2] = pk(v.x, v.y); B[3] = pk(v.z, v.w);                       \
  }

// One LDS chunk against 3 weight vectors (rows t=0,1,2).
#define DOTK(HSRC, IDX, A, B, C)                                               \
  {                                                                            \
    u32x4 h4 = HSRC[(IDX)];                                                    \
    acc0 = fdot2(A[0], h4[0], acc0); acc0 = fdot2(A[1], h4[1], acc0);          \
    acc0 = fdot2(A[2], h4[2], acc0); acc0 = fdot2(A[3], h4[3], acc0);          \
    acc1 = fdot2(B[0], h4[0], acc1); acc1 = fdot2(B[1], h4[1], acc1);          \
    acc1 = fdot2(B[2], h4[2], acc1); acc1 = fdot2(B[3], h4[3], acc1);          \
    acc2 = fdot2(C[0], h4[0], acc2); acc2 = fdot2(C[1], h4[1], acc2);          \
    acc2 = fdot2(C[2], h4[2], acc2); acc2 = fdot2(C[3], h4[3], acc2);          \
  }

// PHASE 1: gru1 over 8192 flat steps (layer0 input = x, 512 cols)
// PHASE 2: gru2 over 256 steps (layer0 input = g_seq2, 1024 cols) + FC tail
// Matrices: m0=Wh_l0, m1=Wi_l1, m2=Wh_l1, m3=Wi_l0.
// 8 waves: wave wv -> matrix m = wv>>1, column half kh = wv&1.
template <int PHASE>
__global__ __launch_bounds__(512, 2) void gru_phase(
    const float* __restrict__ Wm0, const float* __restrict__ Wm1,
    const float* __restrict__ Wm2, const float* __restrict__ Wm3,
    const float* __restrict__ bh0, const float* __restrict__ bi1,
    const float* __restrict__ bh1, const float* __restrict__ bi0,
    const float* __restrict__ x,
    const float* __restrict__ fc1W, const float* __restrict__ fc1b,
    const float* __restrict__ fc2W, const float* __restrict__ fc2b,
    float* __restrict__ out)
{
  constexpr int N0 = (PHASE == 1) ? 8192 : 256;   // flat steps of layer 0
  constexpr int XC = (PHASE == 1) ? 512 : 1024;   // cols of Wm3 (Wi_l0)

  const int wg   = blockIdx.x;          // owns h elements [4*wg, 4*wg+4)
  const int tid  = threadIdx.x;
  const int wv   = tid >> 6;            // wave 0..7
  const int lane = tid & 63;
  const int m    = wv >> 1;             // matrix 0..3
  const int kh   = wv & 1;              // column half
  const int g4   = lane >> 4;           // quarter-wave group
  const int q    = lane & 15;           // position in 16-lane group
  const int j0   = wg * 4;
  const bool m3s = (PHASE == 1) && (m == 3);      // the 512-col matrix

  __shared__ __attribute__((aligned(16))) unsigned sH0[2][512]; // h0[s-1], f16 pairs
  __shared__ __attribute__((aligned(16))) unsigned sH1[2][512]; // h1[s-2]
  __shared__ __attribute__((aligned(16))) unsigned sX [2][512]; // layer-0 input
  __shared__ float sD[2][96];           // partial row dots: [m*24 + kh*12 + rr]
  __shared__ float sY[128];             // FC hidden (phase 2)
  __shared__ int   sRole;               // 1 = this WG is its XCD's relay

  // ---- XCD identification + relay election (runtime-adaptive, no placement
  //      assumption; any XCD with >=1 WG elects exactly one relay) ----
  unsigned xcc;
  asm volatile("s_getreg_b32 %0, hwreg(HW_REG_XCC_ID)" : "=s"(xcc));
  xcc &= 7u;
  if (tid == 0) {
    int old = atomicCAS(&g_relay[xcc], -1, (int)blockIdx.x);
    sRole = (old == -1) ? 1 : 0;
  }

  // ---- this wave's weight rows -> 12 named u32x4 SSA values ----
  u32x4 W0{}, W1{}, W2{}, W3{}, W4{}, W5{}, W6{}, W7{}, W8{}, W9{}, W10{}, W11{};
  {
    const float* Wm = (m == 0) ? Wm0 : (m == 1) ? Wm1 : (m == 2) ? Wm2 : Wm3;
    const int cols = (m == 3) ? XC : 1024;
    if (m3s) {
      LDROW8(0, W0, W1);
      LDROW8(1, W2, W3);
      LDROW8(2, W4, W5);
    } else {
      LDROW16(0, W0, W1, W2,  W3);
      LDROW16(1, W4, W5, W6,  W7);
      LDROW16(2, W8, W9, W10, W11);
    }
  }

  // ---- per-lane gate biases for the combine step (wave 0, lanes 0..7) ----
  float bI0, bI1, bI2, bH0v, bH1v, bH2v;
  {
    const int i = lane & 3, layer = (lane >> 2) & 1;
    const float* pbi = layer ? bi1 : bi0;
    const float* pbh = layer ? bh1 : bh0;
    bI0 = pbi[0 * 1024 + j0 + i]; bI1 = pbi[1 * 1024 + j0 + i]; bI2 = pbi[2 * 1024 + j0 + i];
    bH0v = pbh[0 * 1024 + j0 + i]; bH1v = pbh[1 * 1024 + j0 + i]; bH2v = pbh[2 * 1024 + j0 + i];
  }

  __syncthreads();                      // publish sRole
  const bool isRelay = (sRole != 0);

  // =======================  serial scan  =======================
  for (int s = 0; s <= N0; ++s) {
    const int par = s & 1;

    // issue layer-0 input fetch early (independent of h; overlaps the poll)
    float2 xv = {0.f, 0.f};
    unsigned xs = 0;
    if (PHASE == 1) {
      if (s < N0 && tid < 256) {
        const int b = s & 63, tt = s >> 6;  // flat step s = tt*64 + b
        xv = ((const float2*)(x + (size_t)(b * 128 + tt) * 512))[tid];
      }
    } else {
      if (s < N0) xs = g_seq2[s][tid];
    }

    // ---- obtain records of step s-1 ----
    // relay: poll global records via MALL (sc1), republish into own-XCD
    //        mirror (sc0 -> local L2).
    // consumer: poll own-XCD mirror (sc0, ~local L2 RTT); every 64 spins fall
    //        back to one global sc1 read (guaranteed progress).
    const int t2 = tid & 255;
    {
      unsigned d0 = 0, d1 = 0;
      if (s > 0) {
        const unsigned want = (unsigned)(s - 1);
        const int par2 = (s - 1) & 1;
        const u32x4* ga = (tid < 256) ? &g_recL0[par2][t2] : &g_recL1[par2][t2];
        u32x4 r;
        if (isRelay) {
          r = ld_sc_v4(ga);
          while (r[2] != want) r = ld_sc_v4(ga);
          st_l2_v4(&g_mirror[xcc][par2][tid], r);
        } else {
          const u32x4* mp = &g_mirror[xcc][par2][tid];
          r = ld_l2_v4(mp);
          int spin = 0;
          while (r[2] != want) {
            if (((++spin) & 63) == 0) r = ld_sc_v4(ga);
            else                      r = ld_l2_v4(mp);
          }
        }
        d0 = r[0]; d1 = r[1];
      }
      unsigned* dst = (tid < 256) ? sH0[par] : sH1[par];
      dst[swzH_pos(2 * t2)]     = d0;
      dst[swzH_pos(2 * t2 + 1)] = d1;
    }
    if (PHASE == 1) {
      if (s < N0 && tid < 256) sX[par][swzX_pos(tid)] = pk(xv.x, xv.y);
    } else {
      if (s < N0) sX[par][swzH_pos(tid)] = xs;
    }
    __syncthreads();

    // ---- partial row dots (register weights x LDS f16 operand) ----
    float acc0 = 0.f, acc1 = 0.f, acc2 = 0.f;
    if (m3s) {                                  // Wi_l0 phase1: 512 cols
      const u32x4* Xv = (const u32x4*)sX[par];
      const int base = kh * 32 + 2 * q;
      DOTK(Xv, swzXc(base + 0), W0, W2, W4);
      DOTK(Xv, swzXc(base + 1), W1, W3, W5);
    } else {                                    // 1024-col matvecs, half-K
      const unsigned* hb = (m == 2) ? sH1[par] : (m == 3) ? sX[par] : sH0[par];
      const u32x4* Hv = (const u32x4*)hb;
      const int base = kh * 64 + 4 * q;
      DOTK(Hv, swzHc(base + 0), W0, W4, W8);
      DOTK(Hv, swzHc(base + 1), W1, W5, W9);
      DOTK(Hv, swzHc(base + 2), W2, W6, W10);
      DOTK(Hv, swzHc(base + 3), W3, W7, W11);
    }
    // 16-lane reduction
    acc0 += __shfl_xor(acc0, 8, 16); acc0 += __shfl_xor(acc0, 4, 16);
    acc0 += __shfl_xor(acc0, 2, 16); acc0 += __shfl_xor(acc0, 1, 16);
    acc1 += __shfl_xor(acc1, 8, 16); acc1 += __shfl_xor(acc1, 4, 16);
    acc1 += __shfl_xor(acc1, 2, 16); acc1 += __shfl_xor(acc1, 1, 16);
    acc2 += __shfl_xor(acc2, 8, 16); acc2 += __shfl_xor(acc2, 4, 16);
    acc2 += __shfl_xor(acc2, 2, 16); acc2 += __shfl_xor(acc2, 1, 16);
    if (q < 3) {
      const float dv = (q == 0) ? acc0 : (q == 1) ? acc1 : acc2;
      sD[par][m * 24 + kh * 12 + g4 * 3 + q] = dv;
    }
    __syncthreads();

    // ---- gate combine + record store (wave 0, lanes 0..7 compute) ----
    if (wv == 0) {
      const int i = lane & 3;
      const int layer = (lane >> 2) & 1;
      const float* Sd = sD[par];
      const int mI = layer ? 1 : 3;     // Wi_l1 : Wi_l0
      const int mH = layer ? 2 : 0;     // Wh_l1 : Wh_l0
      const float dIr = Sd[mI * 24 + 0 + i] + Sd[mI * 24 + 12 + 0 + i];
      const float dIz = Sd[mI * 24 + 4 + i] + Sd[mI * 24 + 12 + 4 + i];
      const float dIn = Sd[mI * 24 + 8 + i] + Sd[mI * 24 + 12 + 8 + i];
      const float dHr = Sd[mH * 24 + 0 + i] + Sd[mH * 24 + 12 + 0 + i];
      const float dHz = Sd[mH * 24 + 4 + i] + Sd[mH * 24 + 12 + 4 + i];
      const float dHn = Sd[mH * 24 + 8 + i] + Sd[mH * 24 + 12 + 8 + i];
      const float rg = sigf(dIr + bI0 + dHr + bH0v);
      const float zg = sigf(dIz + bI1 + dHz + bH1v);
      const float ng = tanh_f(dIn + bI2 + rg * (dHn + bH2v));
      const int   jj = 2 * wg + (i >> 1);
      const unsigned hu = (layer ? sH1 : sH0)[par][swzH_pos(jj)];
      const float hp = unpk(hu, i & 1);
      float hn = (1.f - zg) * ng + zg * hp;
      const bool valid = layer ? (s >= 1) : (s < N0);
      hn = valid ? hn : 0.f;
      const float v0 = __shfl(hn, 0), v1 = __shfl(hn, 1);
      const float v2 = __shfl(hn, 2), v3 = __shfl(hn, 3);
      const float w0 = __shfl(hn, 4), w1 = __shfl(hn, 5);
      const float w2 = __shfl(hn, 6), w3 = __shfl(hn, 7);
      if (lane == 0) {
        u32x4 rec0 = {pk(v0, v1), pk(v2, v3), (unsigned)s, 0u};
        u32x4 rec1 = {pk(w0, w1), pk(w2, w3), (unsigned)s, 0u};
        st_sc_v4(&g_recL0[par][wg], rec0);
        st_sc_v4(&g_recL1[par][wg], rec1);
        if (PHASE == 1) {
          if ((s & 63) == 63) {                       // sample hs0[s]
            u32x2 t2v = {rec0[0], rec0[1]};
            st_sc_v2(&g_seq2[2 * (s >> 6)][2 * wg], t2v);
          }
          if (s >= 1 && ((s - 1) & 63) == 63) {       // sample hs1[s-1]
            u32x2 t2v = {rec1[0], rec1[1]};
            st_sc_v2(&g_seq2[2 * ((s - 1) >> 6) + 1][2 * wg], t2v);
          }
        }
      }
    }
    // no trailing sync: next iteration uses the other parity buffers, and its
    // first __syncthreads orders everything.
  }

  // =======================  FC tail (phase 2, WG 0)  =======================
  if (PHASE == 2 && wg == 0) {
    // sH0[0] holds h2_0[255] (staged at s=256). Fetch h2_1[255] (tag 256).
    if (tid < 256) {
      const u32x4* a1 = &g_recL1[0][tid];
      u32x4 r1 = ld_sc_v4(a1);
      while (r1[2] != 256u) r1 = ld_sc_v4(a1);
      sH1[0][swzH_pos(2 * tid)]     = r1[0];
      sH1[0][swzH_pos(2 * tid + 1)] = r1[1];
    }
    __syncthreads();
    if (tid < 128) {
      const int lsel = tid >> 6;        // 0: from h2_0, 1: from h2_1
      const int k = tid & 63;
      const unsigned* Hs = lsel ? sH1[0] : sH0[0];
      const float* wrow = fc1W + (size_t)k * 1024;
      float a = fc1b[k];
      for (int j2 = 0; j2 < 512; ++j2) {
        const unsigned hu = Hs[swzH_pos(j2)];
        a += unpk(hu, 0) * wrow[2 * j2] + unpk(hu, 1) * wrow[2 * j2 + 1];
      }
      sY[tid] = sigf(a);
    }
    __syncthreads();
    if (tid < 2) {
      const float* yv = sY + tid * 64;
      float a = fc2b[0];
      for (int k2 = 0; k2 < 64; ++k2) a += fc2W[k2] * yv[k2];
      out[tid] = sigf(a);
    }
  }
}

extern "C" void kernel_launch(void* const* d_in, const int* in_sizes, int n_in,
                              void* d_out, int out_size, void* d_ws, size_t ws_size,
                              hipStream_t stream) {
  (void)in_sizes; (void)n_in; (void)out_size; (void)d_ws; (void)ws_size;
  const float* x      = (const float*)d_in[0];
  const float* g1_Wi0 = (const float*)d_in[1];
  const float* g1_Wh0 = (const float*)d_in[2];
  const float* g1_bi0 = (const float*)d_in[3];
  const float* g1_bh0 = (const float*)d_in[4];
  const float* g1_Wi1 = (const float*)d_in[5];
  const float* g1_Wh1 = (const float*)d_in[6];
  const float* g1_bi1 = (const float*)d_in[7];
  const float* g1_bh1 = (const float*)d_in[8];
  const float* g2_Wi0 = (const float*)d_in[9];
  const float* g2_Wh0 = (const float*)d_in[10];
  const float* g2_bi0 = (const float*)d_in[11];
  const float* g2_bh0 = (const float*)d_in[12];
  const float* g2_Wi1 = (const float*)d_in[13];
  const float* g2_Wh1 = (const float*)d_in[14];
  const float* g2_bi1 = (const float*)d_in[15];
  const float* g2_bh1 = (const float*)d_in[16];
  const float* fc1W   = (const float*)d_in[17];
  const float* fc1b   = (const float*)d_in[18];
  const float* fc2W   = (const float*)d_in[19];
  const float* fc2b   = (const float*)d_in[20];
  float* out = (float*)d_out;

  init_recs<<<dim3(40), dim3(256), 0, stream>>>();
  gru_phase<1><<<dim3(NWG), dim3(512), 0, stream>>>(
      g1_Wh0, g1_Wi1, g1_Wh1, g1_Wi0, g1_bh0, g1_bi1, g1_bh1, g1_bi0,
      x, fc1W, fc1b, fc2W, fc2b, out);
  init_recs<<<dim3(40), dim3(256), 0, stream>>>();
  gru_phase<2><<<dim3(NWG), dim3(512), 0, stream>>>(
      g2_Wh0, g2_Wi1, g2_Wh1, g2_Wi0, g2_bh0, g2_bi1, g2_bh1, g2_bi0,
      x, fc1W, fc1b, fc2W, fc2b, out);
}

// Round 8
// 25512.999 us; speedup vs baseline: 2.4195x; 2.4195x over previous
//
#include <hip/hip_runtime.h>

// ---------------------------------------------------------------------------
// GRUNet, round 8: per-XCD sync domains (round-7 architecture) + shuffle fix.
//   role0 (XCD0): gru1.l0, 8192 steps, input x            -> g_h0s
//   role1 (XCD1): gru1.l1, input = g_h0s stream           -> g_h1s
//   role2 (XCD2): gru2.l0, 256 steps, input = samples     -> g_q0s
//   role3 (XCD3): gru2.l1 + FC tail                       -> g_q1s, out
// Round-7 bug: publish shuffles executed under `if(tid<8)` -- ds_bpermute
// reads from exec-masked lanes 8..31 are UNDEFINED (ISA), corrupting 3/4 of
// every published record (absmax 5e-2). Fix: shuffles execute with lanes
// 0..31 active (rounds 1-5 proven pattern); only the store is guarded.
// ---------------------------------------------------------------------------

typedef unsigned u32x4 __attribute__((ext_vector_type(4)));
typedef _Float16 h2_t  __attribute__((ext_vector_type(2)));

#define S1 8192
#define S2 256

__device__ u32x4 g_h0s[S1][256];   // records {pair0,pair1,tag,0}
__device__ u32x4 g_h1s[S1][256];
__device__ u32x4 g_q0s[S2][256];
__device__ u32x4 g_q1s[S2][256];
__device__ int   g_claim[128];     // 4 roles x 32 slices

// ---- f16 pack/unpack ----
__device__ __forceinline__ unsigned pk(float a, float b) {
  unsigned short ua = __builtin_bit_cast(unsigned short, (_Float16)a);
  unsigned short ub = __builtin_bit_cast(unsigned short, (_Float16)b);
  return (unsigned)ua | ((unsigned)ub << 16);
}
__device__ __forceinline__ float unpk(unsigned u, int hi) {
  unsigned short us = (unsigned short)(hi ? (u >> 16) : (u & 0xffffu));
  return (float)__builtin_bit_cast(_Float16, us);
}

#if __has_builtin(__builtin_amdgcn_fdot2)
__device__ __forceinline__ float fdot2(unsigned a, unsigned b, float c) {
  return __builtin_amdgcn_fdot2(__builtin_bit_cast(h2_t, a),
                                __builtin_bit_cast(h2_t, b), c, false);
}
#else
__device__ __forceinline__ float fdot2(unsigned a, unsigned b, float c) {
  h2_t ha = __builtin_bit_cast(h2_t, a), hb = __builtin_bit_cast(h2_t, b);
  return c + (float)ha[0] * (float)hb[0] + (float)ha[1] * (float)hb[1];
}
#endif

// ---- scoped 16B loads/stores ----
__device__ __forceinline__ u32x4 ld_sc_v4(const u32x4* p) {   // MALL-coherent
  u32x4 v;
  asm volatile("global_load_dwordx4 %0, %1, off sc1\n\t"
               "s_waitcnt vmcnt(0)" : "=&v"(v) : "v"(p) : "memory");
  return v;
}
__device__ __forceinline__ u32x4 ld_l2_v4(const u32x4* p) {   // own-L2
  u32x4 v;
  asm volatile("global_load_dwordx4 %0, %1, off sc0\n\t"
               "s_waitcnt vmcnt(0)" : "=&v"(v) : "v"(p) : "memory");
  return v;
}
__device__ __forceinline__ void st_sc_v4(u32x4* p, u32x4 v) { // write-through
  asm volatile("global_store_dwordx4 %0, %1, off sc1" :: "v"(p), "v"(v) : "memory");
}

// ---- fast activations ----
__device__ __forceinline__ float rcpf(float x) {
#if __has_builtin(__builtin_amdgcn_rcpf)
  return __builtin_amdgcn_rcpf(x);
#else
  return 1.f / x;
#endif
}
__device__ __forceinline__ float sigf(float x) { return rcpf(1.f + __expf(-x)); }
__device__ __forceinline__ float tanh_f(float x) {
  x = fminf(fmaxf(x, -15.f), 15.f);
  const float e = __expf(2.f * x);
  return (e - 1.f) * rcpf(e + 1.f);
}

// ---- LDS swizzles (16B-chunk XOR) ----
__device__ __forceinline__ int swzHc(int ch) { return ch ^ ((ch >> 3) & 7); } // 128 chunks
__device__ __forceinline__ int swzH_pos(int i) { return (swzHc(i >> 2) << 2) | (i & 3); }
__device__ __forceinline__ int swzXc(int ch) { return ch ^ ((ch >> 2) & 7); } // 64 chunks
__device__ __forceinline__ int swzX_pos(int i) { return (swzXc(i >> 2) << 2) | (i & 3); }

__global__ void init_all() {
  const long long NH = (long long)S1 * 256;
  const long long NQ = (long long)S2 * 256;
  const long long N  = 2 * NH + 2 * NQ;
  for (long long k = (long long)blockIdx.x * blockDim.x + threadIdx.x; k < N;
       k += (long long)gridDim.x * blockDim.x) {
    u32x4* r;
    long long k2 = k;
    if (k2 < NH) r = &g_h0s[0][0] + k2;
    else {
      k2 -= NH;
      if (k2 < NH) r = &g_h1s[0][0] + k2;
      else {
        k2 -= NH;
        if (k2 < NQ) r = &g_q0s[0][0] + k2;
        else         r = &g_q1s[0][0] + (k2 - NQ);
      }
    }
    (*r)[2] = 0xFFFFFFFFu;
  }
  if (blockIdx.x == 0 && threadIdx.x < 128) g_claim[threadIdx.x] = 0;
}

__device__ __forceinline__ const u32x4* in_addr(int role, int u, int r) {
  if (role == 1) return &g_h0s[u][r];
  if (role == 2) {
    const int ss = ((u >> 1) << 6) + 63;
    return (u & 1) ? &g_h1s[ss][r] : &g_h0s[ss][r];
  }
  return &g_q0s[u][r];
}
__device__ __forceinline__ unsigned in_want(int role, int u) {
  return (role == 2) ? (unsigned)(((u >> 1) << 6) + 63) : (unsigned)u;
}

#define MAC4(A, W4, H4)                                                       \
  A = fdot2((W4)[0], (H4)[0], A); A = fdot2((W4)[1], (H4)[1], A);             \
  A = fdot2((W4)[2], (H4)[2], A); A = fdot2((W4)[3], (H4)[3], A);

#define RED16(A)                                                              \
  A += __shfl_xor(A, 8, 16); A += __shfl_xor(A, 4, 16);                       \
  A += __shfl_xor(A, 2, 16); A += __shfl_xor(A, 1, 16);

__global__
__attribute__((amdgpu_flat_work_group_size(512, 512), amdgpu_waves_per_eu(2, 2)))
void gru_all(const float* __restrict__ x,
             const float* __restrict__ g1_Wi0, const float* __restrict__ g1_Wh0,
             const float* __restrict__ g1_bi0, const float* __restrict__ g1_bh0,
             const float* __restrict__ g1_Wi1, const float* __restrict__ g1_Wh1,
             const float* __restrict__ g1_bi1, const float* __restrict__ g1_bh1,
             const float* __restrict__ g2_Wi0, const float* __restrict__ g2_Wh0,
             const float* __restrict__ g2_bi0, const float* __restrict__ g2_bh0,
             const float* __restrict__ g2_Wi1, const float* __restrict__ g2_Wh1,
             const float* __restrict__ g2_bi1, const float* __restrict__ g2_bh1,
             const float* __restrict__ fc1W, const float* __restrict__ fc1b,
             const float* __restrict__ fc2W, const float* __restrict__ fc2b,
             float* __restrict__ out)
{
  const int tid = threadIdx.x;
  const int G   = tid >> 4;            // 32 groups of 16 lanes
  const int q   = tid & 15;
  const int rid = tid - 256;           // stream-thread id (valid for tid>=256)

  __shared__ __attribute__((aligned(16))) unsigned sH[2][512];   // own h[s-1]
  __shared__ __attribute__((aligned(16))) unsigned sIN[8][512];  // stream ring
  __shared__ __attribute__((aligned(16))) unsigned sX[8][256];   // x ring (role0)
  __shared__ float sD[96];             // Wh row dots (rr = gate*32+elem)
  __shared__ float sDI[96];            // Wi row dots
  __shared__ float sY[128];
  __shared__ int   sSlot;

  // ---- slot claim: prefer own-XCD role; bounded global fallback ----
  unsigned xcc;
  asm volatile("s_getreg_b32 %0, hwreg(HW_REG_XCC_ID)" : "=s"(xcc));
  xcc &= 7u;
  if (tid == 0) {
    int slot = -1;
    if (xcc < 4u) {
      for (int i = 0; i < 32 && slot < 0; ++i)
        if (atomicCAS(&g_claim[(int)xcc * 32 + i], 0, 1) == 0)
          slot = (int)xcc * 32 + i;
    }
    if (slot < 0) {
      for (int k = 0; k < 32; ++k) __builtin_amdgcn_s_sleep(64);  // ~60us
      for (int i = 0; i < 128 && slot < 0; ++i)
        if (atomicCAS(&g_claim[i], 0, 1) == 0) slot = i;
    }
    sSlot = slot;
  }
  __syncthreads();
  const int slot = sSlot;
  if (slot < 0) return;                // surplus WG (exits before loop barriers)
  const int role = slot >> 5;          // 0..3
  const int rank = slot & 31;          // h-slice [32*rank, +32)
  const int e0   = rank * 32;
  const bool lp  = ((int)xcc == role); // recurrence local to this XCD's L2?
  const int S    = (role <= 1) ? S1 : S2;

  const float* Wh  = (role == 0) ? g1_Wh0 : (role == 1) ? g1_Wh1
                   : (role == 2) ? g2_Wh0 : g2_Wh1;
  const float* Wi  = (role == 0) ? g1_Wi0 : (role == 1) ? g1_Wi1
                   : (role == 2) ? g2_Wi0 : g2_Wi1;
  const float* pbi = (role == 0) ? g1_bi0 : (role == 1) ? g1_bi1
                   : (role == 2) ? g2_bi0 : g2_bi1;
  const float* pbh = (role == 0) ? g1_bh0 : (role == 1) ? g1_bh1
                   : (role == 2) ? g2_bh0 : g2_bh1;
  u32x4 (*outA)[256] = (role == 0) ? g_h0s : (role == 1) ? g_h1s
                     : (role == 2) ? g_q0s : g_q1s;

  // ---- weights -> registers: group (G) owns 6 rows of ONE matrix ----
  // Wh groups: G<16, rows rr=G*6+j. Wi groups: G>=16, rows rr=(G-16)*6+j.
  // rr = gate*32 + elem; global row R = gate*1024 + e0 + elem.
  // lane q covers cols [64q,64q+64) (1024-col) or [32q,32q+32) (role0 Wi).
  u32x4 wv[6][8];
  {
    const bool isWh = (G < 16);
    const int  Gm   = isWh ? G : (G - 16);
    const float* M  = isWh ? Wh : Wi;
    const bool wide = isWh || (role != 0);
    #pragma unroll
    for (int j = 0; j < 6; ++j) {
      const int rr = Gm * 6 + j;
      const int R  = (rr >> 5) * 1024 + e0 + (rr & 31);
      if (wide) {
        const float4* rp = (const float4*)(M + (size_t)R * 1024 + 64 * q);
        #pragma unroll
        for (int c = 0; c < 8; ++c) {
          float4 a = rp[2 * c], b = rp[2 * c + 1];
          wv[j][c] = (u32x4){pk(a.x, a.y), pk(a.z, a.w), pk(b.x, b.y), pk(b.z, b.w)};
        }
      } else {
        const float4* rp = (const float4*)(M + (size_t)R * 512 + 32 * q);
        #pragma unroll
        for (int c = 0; c < 4; ++c) {
          float4 a = rp[2 * c], b = rp[2 * c + 1];
          wv[j][c] = (u32x4){pk(a.x, a.y), pk(a.z, a.w), pk(b.x, b.y), pk(b.z, b.w)};
        }
      }
    }
  }

  // ---- biases for combine lanes (tid<32 -> elem e0+tid) ----
  float bIr = 0, bIz = 0, bIn = 0, bHr = 0, bHz = 0, bHn = 0;
  if (tid < 32) {
    const int ge = e0 + tid;
    bIr = pbi[ge]; bIz = pbi[1024 + ge]; bIn = pbi[2048 + ge];
    bHr = pbh[ge]; bHz = pbh[1024 + ge]; bHn = pbh[2048 + ge];
  }

  // ---- stream prologue: fill ring slots 0..3 ----
  if (tid >= 256) {
    if (role == 0) {
      #pragma unroll
      for (int u = 0; u < 4; ++u) {
        float2 xv = ((const float2*)(x + (size_t)((u & 63) * 128 + (u >> 6)) * 512))[rid];
        sX[u][swzX_pos(rid)] = pk(xv.x, xv.y);
      }
    } else {
      for (int u = 0; u < 4; ++u) {
        const u32x4* a = in_addr(role, u, rid);
        const unsigned w = in_want(role, u);
        u32x4 r = ld_sc_v4(a);
        while (r[2] != w) r = ld_sc_v4(a);
        sIN[u][swzH_pos(2 * rid)]     = r[0];
        sIN[u][swzH_pos(2 * rid + 1)] = r[1];
      }
    }
  }
  __syncthreads();

  // =======================  serial scan  =======================
  for (int s = 0; s < S; ++s) {
    const int par = s & 1;

    // ---- stream batch-fetch: every 4th iter, steps s+4..s+7 (tid>=256) ----
    if (tid >= 256 && (s & 3) == 0) {
      if (role == 0) {
        #pragma unroll
        for (int k = 0; k < 4; ++k) {
          const int u = s + 4 + k;
          if (u < S) {
            float2 xv = ((const float2*)(x + (size_t)((u & 63) * 128 + (u >> 6)) * 512))[rid];
            sX[u & 7][swzX_pos(rid)] = pk(xv.x, xv.y);
          }
        }
      } else {
        #pragma unroll
        for (int k = 0; k < 4; ++k) {
          const int u = s + 4 + k;
          if (u < S) {
            const u32x4* a = in_addr(role, u, rid);
            const unsigned w = in_want(role, u);
            u32x4 r = ld_sc_v4(a);
            while (r[2] != w) r = ld_sc_v4(a);
            sIN[u & 7][swzH_pos(2 * rid)]     = r[0];
            sIN[u & 7][swzH_pos(2 * rid + 1)] = r[1];
          }
        }
      }
    }

    // ---- own recurrence poll (tid<256; the true serial dependency) ----
    if (tid < 256) {
      unsigned d0 = 0, d1 = 0;
      if (s > 0) {
        const unsigned w = (unsigned)(s - 1);
        const u32x4* a = &outA[s - 1][tid];
        u32x4 r;
        if (lp) {
          r = ld_l2_v4(a);
          int spin = 0;
          while (r[2] != w)
            r = (((++spin) & 7) == 0) ? ld_sc_v4(a) : ld_l2_v4(a);
        } else {
          r = ld_sc_v4(a);
          while (r[2] != w) r = ld_sc_v4(a);
        }
        d0 = r[0]; d1 = r[1];
      }
      sH[par][swzH_pos(2 * tid)]     = d0;
      sH[par][swzH_pos(2 * tid + 1)] = d1;
    }
    __syncthreads();                                   // barrier 1

    // ---- row dots (register weights x LDS operand) ----
    float a0 = 0, a1 = 0, a2 = 0, a3 = 0, a4 = 0, a5 = 0;
    if (G < 16) {                                      // Wh groups: h[s-1]
      const u32x4* HV = (const u32x4*)sH[par];
      #pragma unroll
      for (int c = 0; c < 8; ++c) {
        const u32x4 h4 = HV[8 * q + (c ^ (q & 7))];
        MAC4(a0, wv[0][c], h4); MAC4(a1, wv[1][c], h4); MAC4(a2, wv[2][c], h4);
        MAC4(a3, wv[3][c], h4); MAC4(a4, wv[4][c], h4); MAC4(a5, wv[5][c], h4);
      }
    } else if (role != 0) {                            // Wi groups: stream
      const u32x4* IV = (const u32x4*)sIN[s & 7];
      #pragma unroll
      for (int c = 0; c < 8; ++c) {
        const u32x4 h4 = IV[8 * q + (c ^ (q & 7))];
        MAC4(a0, wv[0][c], h4); MAC4(a1, wv[1][c], h4); MAC4(a2, wv[2][c], h4);
        MAC4(a3, wv[3][c], h4); MAC4(a4, wv[4][c], h4); MAC4(a5, wv[5][c], h4);
      }
    } else {                                           // role0 Wi: x (512 col)
      const u32x4* XV = (const u32x4*)sX[s & 7];
      #pragma unroll
      for (int c = 0; c < 4; ++c) {
        const int ch = 4 * q + c;
        const u32x4 h4 = XV[ch ^ ((ch >> 2) & 7)];
        MAC4(a0, wv[0][c], h4); MAC4(a1, wv[1][c], h4); MAC4(a2, wv[2][c], h4);
        MAC4(a3, wv[3][c], h4); MAC4(a4, wv[4][c], h4); MAC4(a5, wv[5][c], h4);
      }
    }
    RED16(a0); RED16(a1); RED16(a2); RED16(a3); RED16(a4); RED16(a5);
    if (q < 6) {
      const float v = (q == 0) ? a0 : (q == 1) ? a1 : (q == 2) ? a2
                    : (q == 3) ? a3 : (q == 4) ? a4 : a5;
      if (G < 16) sD[G * 6 + q] = v;
      else        sDI[(G - 16) * 6 + q] = v;
    }
    __syncthreads();                                   // barrier 2

    // ---- gate combine + publish (lanes 0..31 of wave 0) ----
    if (tid < 32) {
      const float rg = sigf(sDI[tid] + bIr + sD[tid] + bHr);
      const float zg = sigf(sDI[32 + tid] + bIz + sD[32 + tid] + bHz);
      const float ng = tanh_f(sDI[64 + tid] + bIn + rg * (sD[64 + tid] + bHn));
      const int ge = e0 + tid;
      const float hp = unpk(sH[par][swzH_pos(ge >> 1)], ge & 1);
      const float hn = (1.f - zg) * ng + zg * hp;
      // shuffles executed by ALL 32 lanes (ds_bpermute reads from
      // exec-masked-off lanes are undefined -- round-7 bug); store guarded.
      const int b4 = (tid & 7) * 4;
      const float v0 = __shfl(hn, b4),     v1 = __shfl(hn, b4 + 1);
      const float v2 = __shfl(hn, b4 + 2), v3 = __shfl(hn, b4 + 3);
      if (tid < 8) {
        u32x4 rec = {pk(v0, v1), pk(v2, v3), (unsigned)s, 0u};
        st_sc_v4(&outA[s][rank * 8 + tid], rec);
      }
    }
    // next iter's barrier1 orders all buffer reuse
  }

  // =======================  FC tail (role 3, rank 0)  ========================
  if (role == 3 && rank == 0) {
    if (tid < 256) {                    // h2_0[255] -> sH[0]
      const u32x4* a = &g_q0s[S2 - 1][tid];
      u32x4 r = ld_sc_v4(a);
      while (r[2] != (unsigned)(S2 - 1)) r = ld_sc_v4(a);
      sH[0][swzH_pos(2 * tid)]     = r[0];
      sH[0][swzH_pos(2 * tid + 1)] = r[1];
    } else {                            // h2_1[255] -> sH[1]
      const u32x4* a = &g_q1s[S2 - 1][rid];
      u32x4 r = ld_sc_v4(a);
      while (r[2] != (unsigned)(S2 - 1)) r = ld_sc_v4(a);
      sH[1][swzH_pos(2 * rid)]     = r[0];
      sH[1][swzH_pos(2 * rid + 1)] = r[1];
    }
    __syncthreads();
    if (tid < 128) {
      const int l = tid >> 6, k = tid & 63;
      const unsigned* Hs = (const unsigned*)sH[l];
      const float* wrow = fc1W + (size_t)k * 1024;
      float acc = fc1b[k];
      for (int j2 = 0; j2 < 512; ++j2) {
        const unsigned hu = Hs[swzH_pos(j2)];
        acc += unpk(hu, 0) * wrow[2 * j2] + unpk(hu, 1) * wrow[2 * j2 + 1];
      }
      sY[tid] = sigf(acc);
    }
    __syncthreads();
    if (tid < 2) {
      const float* yv = sY + tid * 64;
      float acc = fc2b[0];
      for (int k2 = 0; k2 < 64; ++k2) acc += fc2W[k2] * yv[k2];
      out[tid] = sigf(acc);
    }
  }
}

extern "C" void kernel_launch(void* const* d_in, const int* in_sizes, int n_in,
                              void* d_out, int out_size, void* d_ws, size_t ws_size,
                              hipStream_t stream) {
  (void)in_sizes; (void)n_in; (void)out_size; (void)d_ws; (void)ws_size;
  const float* x      = (const float*)d_in[0];
  const float* g1_Wi0 = (const float*)d_in[1];
  const float* g1_Wh0 = (const float*)d_in[2];
  const float* g1_bi0 = (const float*)d_in[3];
  const float* g1_bh0 = (const float*)d_in[4];
  const float* g1_Wi1 = (const float*)d_in[5];
  const float* g1_Wh1 = (const float*)d_in[6];
  const float* g1_bi1 = (const float*)d_in[7];
  const float* g1_bh1 = (const float*)d_in[8];
  const float* g2_Wi0 = (const float*)d_in[9];
  const float* g2_Wh0 = (const float*)d_in[10];
  const float* g2_bi0 = (const float*)d_in[11];
  const float* g2_bh0 = (const float*)d_in[12];
  const float* g2_Wi1 = (const float*)d_in[13];
  const float* g2_Wh1 = (const float*)d_in[14];
  const float* g2_bi1 = (const float*)d_in[15];
  const float* g2_bh1 = (const float*)d_in[16];
  const float* fc1W   = (const float*)d_in[17];
  const float* fc1b   = (const float*)d_in[18];
  const float* fc2W   = (const float*)d_in[19];
  const float* fc2b   = (const float*)d_in[20];
  float* out = (float*)d_out;

  init_all<<<dim3(2048), dim3(256), 0, stream>>>();
  gru_all<<<dim3(256), dim3(512), 0, stream>>>(
      x, g1_Wi0, g1_Wh0, g1_bi0, g1_bh0, g1_Wi1, g1_Wh1, g1_bi1, g1_bh1,
      g2_Wi0, g2_Wh0, g2_bi0, g2_bh0, g2_Wi1, g2_Wh1, g2_bi1, g2_bh1,
      fc1W, fc1b, fc2W, fc2b, out);
}

// Round 10
// 25354.735 us; speedup vs baseline: 2.4346x; 1.0062x over previous
//
#include <hip/hip_runtime.h>

// ---------------------------------------------------------------------------
// GRUNet, round 10: round-8 architecture (passing, 25.5ms) + ONE lever:
// local sc0 publish. r8 evidence: all heads sit on their role's XCD (claim
// verified), yet sc0 polls of sc1-stored records never succeed -> pacing on
// the 1-in-8 sc1 fallback (~3.1us/step). Model: sc1 store = write-through to
// MALL, does NOT deposit in producer's own L2. Fix: producers ALSO store each
// record sc0 (write-back -> dirty line in own-XCD L2) into private
// g_loc[role][parity]; same-XCD pollers poll g_loc sc0 (local L2 hit),
// keeping the sc1 stream fallback. Worst case = r8 behavior, never a hang.
//   role r on XCD r: 32 WGs, each owns 32 h-elems of layer r's scan.
//   roles: 0=gru1.l0 (in=x) 1=gru1.l1 (in=h0s) 2=gru2.l0 (in=samples)
//          3=gru2.l1 (in=q0s) + FC tail.
// ---------------------------------------------------------------------------

typedef unsigned u32x4 __attribute__((ext_vector_type(4)));
typedef _Float16 h2_t  __attribute__((ext_vector_type(2)));

#define S1 8192
#define S2 256

__device__ u32x4 g_h0s[S1][256];   // records {pair0,pair1,tag,0}
__device__ u32x4 g_h1s[S1][256];
__device__ u32x4 g_q0s[S2][256];
__device__ u32x4 g_q1s[S2][256];
__device__ u32x4 g_loc[4][2][256]; // local (sc0, own-XCD L2) recurrence records
__device__ int   g_claim[128];     // 4 roles x 32 slices

// ---- f16 pack/unpack ----
__device__ __forceinline__ unsigned pk(float a, float b) {
  unsigned short ua = __builtin_bit_cast(unsigned short, (_Float16)a);
  unsigned short ub = __builtin_bit_cast(unsigned short, (_Float16)b);
  return (unsigned)ua | ((unsigned)ub << 16);
}
__device__ __forceinline__ float unpk(unsigned u, int hi) {
  unsigned short us = (unsigned short)(hi ? (u >> 16) : (u & 0xffffu));
  return (float)__builtin_bit_cast(_Float16, us);
}

#if __has_builtin(__builtin_amdgcn_fdot2)
__device__ __forceinline__ float fdot2(unsigned a, unsigned b, float c) {
  return __builtin_amdgcn_fdot2(__builtin_bit_cast(h2_t, a),
                                __builtin_bit_cast(h2_t, b), c, false);
}
#else
__device__ __forceinline__ float fdot2(unsigned a, unsigned b, float c) {
  h2_t ha = __builtin_bit_cast(h2_t, a), hb = __builtin_bit_cast(h2_t, b);
  return c + (float)ha[0] * (float)hb[0] + (float)ha[1] * (float)hb[1];
}
#endif

// ---- scoped 16B loads/stores ----
__device__ __forceinline__ u32x4 ld_sc_v4(const u32x4* p) {   // MALL-coherent
  u32x4 v;
  asm volatile("global_load_dwordx4 %0, %1, off sc1\n\t"
               "s_waitcnt vmcnt(0)" : "=&v"(v) : "v"(p) : "memory");
  return v;
}
__device__ __forceinline__ u32x4 ld_l2_v4(const u32x4* p) {   // own L2
  u32x4 v;
  asm volatile("global_load_dwordx4 %0, %1, off sc0\n\t"
               "s_waitcnt vmcnt(0)" : "=&v"(v) : "v"(p) : "memory");
  return v;
}
__device__ __forceinline__ void st_sc_v4(u32x4* p, u32x4 v) { // -> MALL
  asm volatile("global_store_dwordx4 %0, %1, off sc1" :: "v"(p), "v"(v) : "memory");
}
__device__ __forceinline__ void st_l2_v4(u32x4* p, u32x4 v) { // -> own L2 (dirty)
  asm volatile("global_store_dwordx4 %0, %1, off sc0" :: "v"(p), "v"(v) : "memory");
}

// ---- fast activations ----
__device__ __forceinline__ float rcpf(float x) {
#if __has_builtin(__builtin_amdgcn_rcpf)
  return __builtin_amdgcn_rcpf(x);
#else
  return 1.f / x;
#endif
}
__device__ __forceinline__ float sigf(float x) { return rcpf(1.f + __expf(-x)); }
__device__ __forceinline__ float tanh_f(float x) {
  x = fminf(fmaxf(x, -15.f), 15.f);
  const float e = __expf(2.f * x);
  return (e - 1.f) * rcpf(e + 1.f);
}

// ---- LDS swizzles (16B-chunk XOR) ----
__device__ __forceinline__ int swzHc(int ch) { return ch ^ ((ch >> 3) & 7); } // 128 chunks
__device__ __forceinline__ int swzH_pos(int i) { return (swzHc(i >> 2) << 2) | (i & 3); }
__device__ __forceinline__ int swzX_pos(int i) {
  int ch = i >> 2; ch ^= (ch >> 2) & 7; return (ch << 2) | (i & 3);
}

__global__ void init_all() {
  const long long NH = (long long)S1 * 256;
  const long long NQ = (long long)S2 * 256;
  const long long NL = 4LL * 2 * 256;
  const long long N  = 2 * NH + 2 * NQ + NL;
  u32x4 ff = {0u, 0u, 0xFFFFFFFFu, 0u};
  for (long long k = (long long)blockIdx.x * blockDim.x + threadIdx.x; k < N;
       k += (long long)gridDim.x * blockDim.x) {
    u32x4* r;
    long long k2 = k;
    if (k2 < NH) r = &g_h0s[0][0] + k2;
    else {
      k2 -= NH;
      if (k2 < NH) r = &g_h1s[0][0] + k2;
      else {
        k2 -= NH;
        if (k2 < NQ) r = &g_q0s[0][0] + k2;
        else {
          k2 -= NQ;
          if (k2 < NQ) r = &g_q1s[0][0] + k2;
          else         r = &g_loc[0][0][0] + (k2 - NQ);
        }
      }
    }
    *r = ff;
  }
  if (blockIdx.x == 0 && threadIdx.x < 128) g_claim[threadIdx.x] = 0;
}

__device__ __forceinline__ const u32x4* in_addr(int role, int u, int r) {
  if (role == 1) return &g_h0s[u][r];
  if (role == 2) {
    const int ss = ((u >> 1) << 6) + 63;
    return (u & 1) ? &g_h1s[ss][r] : &g_h0s[ss][r];
  }
  return &g_q0s[u][r];
}
__device__ __forceinline__ unsigned in_want(int role, int u) {
  return (role == 2) ? (unsigned)(((u >> 1) << 6) + 63) : (unsigned)u;
}

#define MAC4(A, W4, H4)                                                       \
  A = fdot2((W4)[0], (H4)[0], A); A = fdot2((W4)[1], (H4)[1], A);             \
  A = fdot2((W4)[2], (H4)[2], A); A = fdot2((W4)[3], (H4)[3], A);

#define RED16(A)                                                              \
  A += __shfl_xor(A, 8, 16); A += __shfl_xor(A, 4, 16);                       \
  A += __shfl_xor(A, 2, 16); A += __shfl_xor(A, 1, 16);

__global__
__attribute__((amdgpu_flat_work_group_size(512, 512), amdgpu_waves_per_eu(2, 2)))
void gru_all(const float* __restrict__ x,
             const float* __restrict__ g1_Wi0, const float* __restrict__ g1_Wh0,
             const float* __restrict__ g1_bi0, const float* __restrict__ g1_bh0,
             const float* __restrict__ g1_Wi1, const float* __restrict__ g1_Wh1,
             const float* __restrict__ g1_bi1, const float* __restrict__ g1_bh1,
             const float* __restrict__ g2_Wi0, const float* __restrict__ g2_Wh0,
             const float* __restrict__ g2_bi0, const float* __restrict__ g2_bh0,
             const float* __restrict__ g2_Wi1, const float* __restrict__ g2_Wh1,
             const float* __restrict__ g2_bi1, const float* __restrict__ g2_bh1,
             const float* __restrict__ fc1W, const float* __restrict__ fc1b,
             const float* __restrict__ fc2W, const float* __restrict__ fc2b,
             float* __restrict__ out)
{
  const int tid = threadIdx.x;
  const int G   = tid >> 4;            // 32 groups of 16 lanes
  const int q   = tid & 15;
  const int rid = tid - 256;           // stream-thread id (valid for tid>=256)

  __shared__ __attribute__((aligned(16))) unsigned sH[2][512];   // own h[s-1]
  __shared__ __attribute__((aligned(16))) unsigned sIN[8][512];  // stream ring
  __shared__ __attribute__((aligned(16))) unsigned sX[8][256];   // x ring (role0)
  __shared__ float sD[96];             // Wh row dots (rr = gate*32+elem)
  __shared__ float sDI[96];            // Wi row dots
  __shared__ float sY[128];
  __shared__ int   sSlot;

  // ---- slot claim: prefer own-XCD role; bounded global fallback ----
  unsigned xcc;
  asm volatile("s_getreg_b32 %0, hwreg(HW_REG_XCC_ID)" : "=s"(xcc));
  xcc &= 7u;
  if (tid == 0) {
    int slot = -1;
    if (xcc < 4u) {
      for (int i = 0; i < 32 && slot < 0; ++i)
        if (atomicCAS(&g_claim[(int)xcc * 32 + i], 0, 1) == 0)
          slot = (int)xcc * 32 + i;
    }
    if (slot < 0) {
      for (int k = 0; k < 32; ++k) __builtin_amdgcn_s_sleep(64);  // ~60us
      for (int i = 0; i < 128 && slot < 0; ++i)
        if (atomicCAS(&g_claim[i], 0, 1) == 0) slot = i;
    }
    sSlot = slot;
  }
  __syncthreads();
  const int slot = sSlot;
  if (slot < 0) return;                // surplus WG (exits before loop barriers)
  const int role = slot >> 5;          // 0..3
  const int rank = slot & 31;          // h-slice [32*rank, +32)
  const int e0   = rank * 32;
  const bool lp  = ((int)xcc == role); // recurrence local to this XCD's L2?
  const int S    = (role <= 1) ? S1 : S2;

  const float* Wh  = (role == 0) ? g1_Wh0 : (role == 1) ? g1_Wh1
                   : (role == 2) ? g2_Wh0 : g2_Wh1;
  const float* Wi  = (role == 0) ? g1_Wi0 : (role == 1) ? g1_Wi1
                   : (role == 2) ? g2_Wi0 : g2_Wi1;
  const float* pbi = (role == 0) ? g1_bi0 : (role == 1) ? g1_bi1
                   : (role == 2) ? g2_bi0 : g2_bi1;
  const float* pbh = (role == 0) ? g1_bh0 : (role == 1) ? g1_bh1
                   : (role == 2) ? g2_bh0 : g2_bh1;
  u32x4 (*outA)[256] = (role == 0) ? g_h0s : (role == 1) ? g_h1s
                     : (role == 2) ? g_q0s : g_q1s;

  // ---- weights -> registers: group (G) owns 6 rows of ONE matrix ----
  u32x4 wv[6][8];
  {
    const bool isWh = (G < 16);
    const int  Gm   = isWh ? G : (G - 16);
    const float* M  = isWh ? Wh : Wi;
    const bool wide = isWh || (role != 0);
    #pragma unroll
    for (int j = 0; j < 6; ++j) {
      const int rr = Gm * 6 + j;
      const int R  = (rr >> 5) * 1024 + e0 + (rr & 31);
      if (wide) {
        const float4* rp = (const float4*)(M + (size_t)R * 1024 + 64 * q);
        #pragma unroll
        for (int c = 0; c < 8; ++c) {
          float4 a = rp[2 * c], b = rp[2 * c + 1];
          wv[j][c] = (u32x4){pk(a.x, a.y), pk(a.z, a.w), pk(b.x, b.y), pk(b.z, b.w)};
        }
      } else {
        const float4* rp = (const float4*)(M + (size_t)R * 512 + 32 * q);
        #pragma unroll
        for (int c = 0; c < 4; ++c) {
          float4 a = rp[2 * c], b = rp[2 * c + 1];
          wv[j][c] = (u32x4){pk(a.x, a.y), pk(a.z, a.w), pk(b.x, b.y), pk(b.z, b.w)};
        }
      }
    }
  }

  // ---- biases for combine lanes (tid<32 -> elem e0+tid) ----
  float bIr = 0, bIz = 0, bIn = 0, bHr = 0, bHz = 0, bHn = 0;
  if (tid < 32) {
    const int ge = e0 + tid;
    bIr = pbi[ge]; bIz = pbi[1024 + ge]; bIn = pbi[2048 + ge];
    bHr = pbh[ge]; bHz = pbh[1024 + ge]; bHn = pbh[2048 + ge];
  }

  // ---- stream prologue: fill ring slots 0..3 ----
  if (tid >= 256) {
    if (role == 0) {
      #pragma unroll
      for (int u = 0; u < 4; ++u) {
        float2 xv = ((const float2*)(x + (size_t)((u & 63) * 128 + (u >> 6)) * 512))[rid];
        sX[u][swzX_pos(rid)] = pk(xv.x, xv.y);
      }
    } else {
      for (int u = 0; u < 4; ++u) {
        const u32x4* a = in_addr(role, u, rid);
        const unsigned w = in_want(role, u);
        u32x4 r = ld_sc_v4(a);
        while (r[2] != w) r = ld_sc_v4(a);
        sIN[u][swzH_pos(2 * rid)]     = r[0];
        sIN[u][swzH_pos(2 * rid + 1)] = r[1];
      }
    }
  }
  __syncthreads();

  // =======================  serial scan  =======================
  for (int s = 0; s < S; ++s) {
    const int par = s & 1;

    // ---- stream batch-fetch: every 4th iter, steps s+4..s+7 (tid>=256) ----
    if (tid >= 256 && (s & 3) == 0) {
      if (role == 0) {
        #pragma unroll
        for (int k = 0; k < 4; ++k) {
          const int u = s + 4 + k;
          if (u < S) {
            float2 xv = ((const float2*)(x + (size_t)((u & 63) * 128 + (u >> 6)) * 512))[rid];
            sX[u & 7][swzX_pos(rid)] = pk(xv.x, xv.y);
          }
        }
      } else {
        #pragma unroll
        for (int k = 0; k < 4; ++k) {
          const int u = s + 4 + k;
          if (u < S) {
            const u32x4* a = in_addr(role, u, rid);
            const unsigned w = in_want(role, u);
            u32x4 r = ld_sc_v4(a);
            while (r[2] != w) r = ld_sc_v4(a);
            sIN[u & 7][swzH_pos(2 * rid)]     = r[0];
            sIN[u & 7][swzH_pos(2 * rid + 1)] = r[1];
          }
        }
      }
    }

    // ---- own recurrence poll (tid<256; the true serial dependency) ----
    // lp: poll g_loc (sc0 -> hits producer's dirty line in our shared L2),
    // 1-in-8 sc1 stream fallback. else: pure sc1 stream.
    if (tid < 256) {
      unsigned d0 = 0, d1 = 0;
      if (s > 0) {
        const unsigned w = (unsigned)(s - 1);
        const u32x4* ga = &outA[s - 1][tid];
        u32x4 r;
        if (lp) {
          const u32x4* la = &g_loc[role][(s - 1) & 1][tid];
          r = ld_l2_v4(la);
          int spin = 0;
          while (r[2] != w)
            r = (((++spin) & 7) == 0) ? ld_sc_v4(ga) : ld_l2_v4(la);
        } else {
          r = ld_sc_v4(ga);
          while (r[2] != w) r = ld_sc_v4(ga);
        }
        d0 = r[0]; d1 = r[1];
      }
      sH[par][swzH_pos(2 * tid)]     = d0;
      sH[par][swzH_pos(2 * tid + 1)] = d1;
    }
    __syncthreads();                                   // barrier 1

    // ---- row dots (register weights x LDS operand) ----
    float a0 = 0, a1 = 0, a2 = 0, a3 = 0, a4 = 0, a5 = 0;
    if (G < 16) {                                      // Wh groups: h[s-1]
      const u32x4* HV = (const u32x4*)sH[par];
      #pragma unroll
      for (int c = 0; c < 8; ++c) {
        const u32x4 h4 = HV[8 * q + (c ^ (q & 7))];
        MAC4(a0, wv[0][c], h4); MAC4(a1, wv[1][c], h4); MAC4(a2, wv[2][c], h4);
        MAC4(a3, wv[3][c], h4); MAC4(a4, wv[4][c], h4); MAC4(a5, wv[5][c], h4);
      }
    } else if (role != 0) {                            // Wi groups: stream
      const u32x4* IV = (const u32x4*)sIN[s & 7];
      #pragma unroll
      for (int c = 0; c < 8; ++c) {
        const u32x4 h4 = IV[8 * q + (c ^ (q & 7))];
        MAC4(a0, wv[0][c], h4); MAC4(a1, wv[1][c], h4); MAC4(a2, wv[2][c], h4);
        MAC4(a3, wv[3][c], h4); MAC4(a4, wv[4][c], h4); MAC4(a5, wv[5][c], h4);
      }
    } else {                                           // role0 Wi: x (512 col)
      const u32x4* XV = (const u32x4*)sX[s & 7];
      #pragma unroll
      for (int c = 0; c < 4; ++c) {
        const int ch = 4 * q + c;
        const u32x4 h4 = XV[ch ^ ((ch >> 2) & 7)];
        MAC4(a0, wv[0][c], h4); MAC4(a1, wv[1][c], h4); MAC4(a2, wv[2][c], h4);
        MAC4(a3, wv[3][c], h4); MAC4(a4, wv[4][c], h4); MAC4(a5, wv[5][c], h4);
      }
    }
    RED16(a0); RED16(a1); RED16(a2); RED16(a3); RED16(a4); RED16(a5);
    if (q < 6) {
      const float v = (q == 0) ? a0 : (q == 1) ? a1 : (q == 2) ? a2
                    : (q == 3) ? a3 : (q == 4) ? a4 : a5;
      if (G < 16) sD[G * 6 + q] = v;
      else        sDI[(G - 16) * 6 + q] = v;
    }
    __syncthreads();                                   // barrier 2

    // ---- gate combine + publish (lanes 0..31 of wave 0) ----
    if (tid < 32) {
      const float rg = sigf(sDI[tid] + bIr + sD[tid] + bHr);
      const float zg = sigf(sDI[32 + tid] + bIz + sD[32 + tid] + bHz);
      const float ng = tanh_f(sDI[64 + tid] + bIn + rg * (sD[64 + tid] + bHn));
      const int ge = e0 + tid;
      const float hp = unpk(sH[par][swzH_pos(ge >> 1)], ge & 1);
      const float hn = (1.f - zg) * ng + zg * hp;
      // shuffles with all 32 source lanes active (r8-proven); store guarded.
      const int b4 = (tid & 7) * 4;
      const float v0 = __shfl(hn, b4),     v1 = __shfl(hn, b4 + 1);
      const float v2 = __shfl(hn, b4 + 2), v3 = __shfl(hn, b4 + 3);
      if (tid < 8) {
        u32x4 rec = {pk(v0, v1), pk(v2, v3), (unsigned)s, 0u};
        if (lp) st_l2_v4(&g_loc[role][s & 1][rank * 8 + tid], rec); // own L2
        st_sc_v4(&outA[s][rank * 8 + tid], rec);                    // MALL
      }
    }
    // next iter's barrier1 orders all buffer reuse
  }

  // =======================  FC tail (role 3, rank 0)  ========================
  if (role == 3 && rank == 0) {
    if (tid < 256) {                    // h2_0[255] -> sH[0]
      const u32x4* a = &g_q0s[S2 - 1][tid];
      u32x4 r = ld_sc_v4(a);
      while (r[2] != (unsigned)(S2 - 1)) r = ld_sc_v4(a);
      sH[0][swzH_pos(2 * tid)]     = r[0];
      sH[0][swzH_pos(2 * tid + 1)] = r[1];
    } else {                            // h2_1[255] -> sH[1]
      const u32x4* a = &g_q1s[S2 - 1][rid];
      u32x4 r = ld_sc_v4(a);
      while (r[2] != (unsigned)(S2 - 1)) r = ld_sc_v4(a);
      sH[1][swzH_pos(2 * rid)]     = r[0];
      sH[1][swzH_pos(2 * rid + 1)] = r[1];
    }
    __syncthreads();
    if (tid < 128) {
      const int l = tid >> 6, k = tid & 63;
      const unsigned* Hs = (const unsigned*)sH[l];
      const float* wrow = fc1W + (size_t)k * 1024;
      float acc = fc1b[k];
      for (int j2 = 0; j2 < 512; ++j2) {
        const unsigned hu = Hs[swzH_pos(j2)];
        acc += unpk(hu, 0) * wrow[2 * j2] + unpk(hu, 1) * wrow[2 * j2 + 1];
      }
      sY[tid] = sigf(acc);
    }
    __syncthreads();
    if (tid < 2) {
      const float* yv = sY + tid * 64;
      float acc = fc2b[0];
      for (int k2 = 0; k2 < 64; ++k2) acc += fc2W[k2] * yv[k2];
      out[tid] = sigf(acc);
    }
  }
}

extern "C" void kernel_launch(void* const* d_in, const int* in_sizes, int n_in,
                              void* d_out, int out_size, void* d_ws, size_t ws_size,
                              hipStream_t stream) {
  (void)in_sizes; (void)n_in; (void)out_size; (void)d_ws; (void)ws_size;
  const float* x      = (const float*)d_in[0];
  const float* g1_Wi0 = (const float*)d_in[1];
  const float* g1_Wh0 = (const float*)d_in[2];
  const float* g1_bi0 = (const float*)d_in[3];
  const float* g1_bh0 = (const float*)d_in[4];
  const float* g1_Wi1 = (const float*)d_in[5];
  const float* g1_Wh1 = (const float*)d_in[6];
  const float* g1_bi1 = (const float*)d_in[7];
  const float* g1_bh1 = (const float*)d_in[8];
  const float* g2_Wi0 = (const float*)d_in[9];
  const float* g2_Wh0 = (const float*)d_in[10];
  const float* g2_bi0 = (const float*)d_in[11];
  const float* g2_bh0 = (const float*)d_in[12];
  const float* g2_Wi1 = (const float*)d_in[13];
  const float* g2_Wh1 = (const float*)d_in[14];
  const float* g2_bi1 = (const float*)d_in[15];
  const float* g2_bh1 = (const float*)d_in[16];
  const float* fc1W   = (const float*)d_in[17];
  const float* fc1b   = (const float*)d_in[18];
  const float* fc2W   = (const float*)d_in[19];
  const float* fc2b   = (const float*)d_in[20];
  float* out = (float*)d_out;

  init_all<<<dim3(2048), dim3(256), 0, stream>>>();
  gru_all<<<dim3(256), dim3(512), 0, stream>>>(
      x, g1_Wi0, g1_Wh0, g1_bi0, g1_bh0, g1_Wi1, g1_Wh1, g1_bi1, g1_bh1,
      g2_Wi0, g2_Wh0, g2_bi0, g2_bh0, g2_Wi1, g2_Wh1, g2_bi1, g2_bh1,
      fc1W, fc1b, fc2W, fc2b, out);
}